// Round 1
// baseline (883.863 us; speedup 1.0000x reference)
//
#include <hip/hip_runtime.h>
#include <hip/hip_bf16.h>

#define NNODES 100000
#define FHID 128
#define NGRAPHS 64
#define NCLASSES 10

__device__ __forceinline__ int lbound(const int* __restrict__ a, int n, int key) {
  int lo = 0, hi = n;
  while (lo < hi) { int mid = (lo + hi) >> 1; if (a[mid] < key) lo = mid + 1; else hi = mid; }
  return lo;
}

// ---- degree histogram (in-degree over col, excluding self loops) ----
__global__ void count_deg_k(const int* __restrict__ col, int E, int* __restrict__ deg) {
  int e = blockIdx.x * 256 + threadIdx.x;
  if (e < E) atomicAdd(&deg[col[e]], 1);
}

// ---- single-block exclusive scan -> csr offsets, fill cursors, dinv ----
__global__ __launch_bounds__(1024) void scan_dinv_k(const int* __restrict__ deg,
    float* __restrict__ dinv, int* __restrict__ coff, int* __restrict__ ccur, int N) {
  __shared__ int sums[1024];
  int t = threadIdx.x;
  int C = (N + 1023) >> 10;            // 98
  int a = t * C, b = min(a + C, N);
  int s = 0;
  for (int i = a; i < b; ++i) s += deg[i];
  sums[t] = s;
  __syncthreads();
  for (int off = 1; off < 1024; off <<= 1) {
    int v = (t >= off) ? sums[t - off] : 0;
    __syncthreads();
    sums[t] += v;
    __syncthreads();
  }
  int run = (t == 0) ? 0 : sums[t - 1];
  for (int i = a; i < b; ++i) {
    int d = deg[i];
    coff[i] = run;
    ccur[i] = run;
    run += d;
    dinv[i] = rsqrtf((float)(d + 1));   // +1 = self loop
  }
  if (t == 1023) coff[N] = run;         // == E
}

// ---- CSR fill: for each edge store its source row under target col ----
__global__ void csr_fill_k(const int* __restrict__ row, const int* __restrict__ col, int E,
                           int* __restrict__ ccur, int* __restrict__ rows) {
  int e = blockIdx.x * 256 + threadIdx.x;
  if (e < E) {
    int p = atomicAdd(&ccur[col[e]], 1);
    rows[p] = row[e];
  }
}

// ---- hs = (act(in) @ W) * dinv[node]  ; 32-node tile, 4n x 4f per thread ----
template<bool RELU>
__global__ __launch_bounds__(256) void gemm_scale_k(const float* __restrict__ in,
    const float* __restrict__ W, const float* __restrict__ dinv, float* __restrict__ out) {
  __shared__ float Wl[FHID * FHID];     // 64 KB
  __shared__ float xl[32 * FHID];       // 16 KB
  int tid = threadIdx.x;
  const float4* W4 = reinterpret_cast<const float4*>(W);
  float4* Wl4 = reinterpret_cast<float4*>(Wl);
  #pragma unroll
  for (int i = 0; i < 16; ++i) Wl4[tid + i * 256] = W4[tid + i * 256];
  int n0 = blockIdx.x * 32;
  const float4* in4 = reinterpret_cast<const float4*>(in + (size_t)n0 * FHID);
  float4* xl4 = reinterpret_cast<float4*>(xl);
  #pragma unroll
  for (int i = 0; i < 4; ++i) {
    float4 v = in4[tid + i * 256];
    if (RELU) {
      v.x = fmaxf(v.x, 0.f); v.y = fmaxf(v.y, 0.f);
      v.z = fmaxf(v.z, 0.f); v.w = fmaxf(v.w, 0.f);
    }
    xl4[tid + i * 256] = v;
  }
  __syncthreads();
  int tf = tid & 31, tn = tid >> 5;
  const float* x0 = xl + (4 * tn + 0) * FHID;
  const float* x1 = xl + (4 * tn + 1) * FHID;
  const float* x2 = xl + (4 * tn + 2) * FHID;
  const float* x3 = xl + (4 * tn + 3) * FHID;
  float4 a0 = {0,0,0,0}, a1 = {0,0,0,0}, a2 = {0,0,0,0}, a3 = {0,0,0,0};
  #pragma unroll 4
  for (int k = 0; k < FHID; ++k) {
    float4 w = *reinterpret_cast<const float4*>(Wl + k * FHID + 4 * tf);
    float v0 = x0[k], v1 = x1[k], v2 = x2[k], v3 = x3[k];
    a0.x += v0 * w.x; a0.y += v0 * w.y; a0.z += v0 * w.z; a0.w += v0 * w.w;
    a1.x += v1 * w.x; a1.y += v1 * w.y; a1.z += v1 * w.z; a1.w += v1 * w.w;
    a2.x += v2 * w.x; a2.y += v2 * w.y; a2.z += v2 * w.z; a2.w += v2 * w.w;
    a3.x += v3 * w.x; a3.y += v3 * w.y; a3.z += v3 * w.z; a3.w += v3 * w.w;
  }
  int nbase = n0 + 4 * tn;
  float d0 = dinv[nbase + 0], d1 = dinv[nbase + 1], d2 = dinv[nbase + 2], d3 = dinv[nbase + 3];
  float4* o4 = reinterpret_cast<float4*>(out);
  float4 r;
  r.x = a0.x * d0; r.y = a0.y * d0; r.z = a0.z * d0; r.w = a0.w * d0;
  o4[(size_t)(nbase + 0) * 32 + tf] = r;
  r.x = a1.x * d1; r.y = a1.y * d1; r.z = a1.z * d1; r.w = a1.w * d1;
  o4[(size_t)(nbase + 1) * 32 + tf] = r;
  r.x = a2.x * d2; r.y = a2.y * d2; r.z = a2.z * d2; r.w = a2.w * d2;
  o4[(size_t)(nbase + 2) * 32 + tf] = r;
  r.x = a3.x * d3; r.y = a3.y * d3; r.z = a3.z * d3; r.w = a3.w * d3;
  o4[(size_t)(nbase + 3) * 32 + tf] = r;
}

// ---- SpMM gather: out[i] = b + dinv[i]*(hs[i] + sum_{j in in(i)} hs[j]) ----
__global__ __launch_bounds__(256) void spmm_k(const float* __restrict__ hs,
    const int* __restrict__ coff, const int* __restrict__ rows,
    const float* __restrict__ dinv, const float* __restrict__ bias, float* __restrict__ out) {
  int node = blockIdx.x * 4 + (threadIdx.x >> 6);
  int lane = threadIdx.x & 63;
  const float2* h2 = reinterpret_cast<const float2*>(hs);
  float2 acc = h2[(size_t)node * 64 + lane];  // self term hs[i]
  float2 acc2 = {0.f, 0.f};
  int s = coff[node], e = coff[node + 1];
  int p = s;
  for (; p + 2 <= e; p += 2) {
    int j0 = rows[p], j1 = rows[p + 1];
    float2 v0 = h2[(size_t)j0 * 64 + lane];
    float2 v1 = h2[(size_t)j1 * 64 + lane];
    acc.x += v0.x; acc.y += v0.y;
    acc2.x += v1.x; acc2.y += v1.y;
  }
  if (p < e) {
    int j = rows[p];
    float2 v = h2[(size_t)j * 64 + lane];
    acc.x += v.x; acc.y += v.y;
  }
  float di = dinv[node];
  float2 b = reinterpret_cast<const float2*>(bias)[lane];
  float2 o;
  o.x = b.x + di * (acc.x + acc2.x);
  o.y = b.y + di * (acc.y + acc2.y);
  reinterpret_cast<float2*>(out)[(size_t)node * 64 + lane] = o;
}

// ---- pooling: per (graph, chunk) block; relu applied here; max via int atomics ----
__global__ __launch_bounds__(128) void pool_k(const float* __restrict__ h,
    const int* __restrict__ batch, float* __restrict__ gfeat) {
  int g = blockIdx.x >> 4;
  int c = blockIdx.x & 15;
  int f = threadIdx.x;
  int lo = lbound(batch, NNODES, g);
  int hi = lbound(batch, NNODES, g + 1);
  int len = hi - lo;
  int cs = lo + ((len * c) >> 4);
  int ce = lo + ((len * (c + 1)) >> 4);
  float mx = 0.f, sm = 0.f;
  for (int n = cs; n < ce; ++n) {
    float v = fmaxf(h[(size_t)n * FHID + f], 0.f);
    mx = fmaxf(mx, v);
    sm += v;
  }
  // relu output >= 0, so int-compare == float-compare; init 0 matches empty->0 semantics
  atomicMax(reinterpret_cast<int*>(&gfeat[g * 256 + f]), __float_as_int(mx));
  atomicAdd(&gfeat[g * 256 + 128 + f], sm);
}

// ---- MLP head + log_softmax: one block per graph ----
__global__ __launch_bounds__(128) void mlp_k(const float* __restrict__ gfeat,
    const int* __restrict__ batch,
    const float* __restrict__ Wl1, const float* __restrict__ bl1,
    const float* __restrict__ Wl2, const float* __restrict__ bl2,
    const float* __restrict__ Wl3, const float* __restrict__ bl3,
    float* __restrict__ out) {
  int g = blockIdx.x;
  int t = threadIdx.x;
  __shared__ float gv[256];
  __shared__ float a1[128];
  __shared__ float a2[64];
  __shared__ float z[NCLASSES];
  __shared__ float red[2];
  int lo = lbound(batch, NNODES, g);
  int hi = lbound(batch, NNODES, g + 1);
  float invc = 1.0f / (float)max(hi - lo, 1);
  gv[t] = gfeat[g * 256 + t];                       // gmp (bits written by atomicMax)
  gv[128 + t] = gfeat[g * 256 + 128 + t] * invc;    // gap = sum/cnt
  __syncthreads();
  float s = bl1[t];
  for (int k = 0; k < 256; ++k) s += gv[k] * Wl1[k * 128 + t];
  a1[t] = fmaxf(s, 0.f);
  __syncthreads();
  if (t < 64) {
    float s2 = bl2[t];
    for (int k = 0; k < 128; ++k) s2 += a1[k] * Wl2[k * 64 + t];
    a2[t] = fmaxf(s2, 0.f);
  }
  __syncthreads();
  if (t < NCLASSES) {
    float s3 = bl3[t];
    for (int k = 0; k < 64; ++k) s3 += a2[k] * Wl3[k * NCLASSES + t];
    z[t] = s3;
  }
  __syncthreads();
  if (t == 0) {
    float m = z[0];
    for (int i = 1; i < NCLASSES; ++i) m = fmaxf(m, z[i]);
    float sum = 0.f;
    for (int i = 0; i < NCLASSES; ++i) sum += expf(z[i] - m);
    red[0] = m; red[1] = logf(sum);
  }
  __syncthreads();
  if (t < NCLASSES) out[g * NCLASSES + t] = z[t] - red[0] - red[1];
}

extern "C" void kernel_launch(void* const* d_in, const int* in_sizes, int n_in,
                              void* d_out, int out_size, void* d_ws, size_t ws_size,
                              hipStream_t stream) {
  const float* x     = (const float*)d_in[0];
  const int*   ei    = (const int*)d_in[1];
  const int*   batch = (const int*)d_in[2];
  const float* W1    = (const float*)d_in[3];
  const float* b1    = (const float*)d_in[4];
  const float* W2    = (const float*)d_in[5];
  const float* b2    = (const float*)d_in[6];
  const float* Wl1   = (const float*)d_in[7];
  const float* bl1   = (const float*)d_in[8];
  const float* Wl2   = (const float*)d_in[9];
  const float* bl2   = (const float*)d_in[10];
  const float* Wl3   = (const float*)d_in[11];
  const float* bl3   = (const float*)d_in[12];
  float* out = (float*)d_out;

  const int N = NNODES;
  const int E = in_sizes[1] / 2;
  const int* row = ei;       // sources
  const int* col = ei + E;   // targets

  char* ws = (char*)d_ws;
  size_t off = 0;
  auto alloc = [&](size_t bytes) {
    size_t cur = off;
    off += (bytes + 255) & ~(size_t)255;
    return (void*)(ws + cur);
  };
  int*   deg   = (int*)alloc((size_t)N * 4);
  float* dinv  = (float*)alloc((size_t)N * 4);
  int*   coff  = (int*)alloc((size_t)(N + 1) * 4);
  int*   ccur  = (int*)alloc((size_t)N * 4);
  int*   crows = (int*)alloc((size_t)E * 4);
  float* bufA  = (float*)alloc((size_t)N * FHID * 4);   // hs (scaled transformed feats)
  float* bufB  = (float*)alloc((size_t)N * FHID * 4);   // conv outputs (pre-relu)
  float* gfeat = (float*)alloc((size_t)NGRAPHS * 256 * 4);

  hipMemsetAsync(deg, 0, (size_t)N * 4, stream);
  hipMemsetAsync(gfeat, 0, (size_t)NGRAPHS * 256 * 4, stream);

  count_deg_k<<<(E + 255) / 256, 256, 0, stream>>>(col, E, deg);
  scan_dinv_k<<<1, 1024, 0, stream>>>(deg, dinv, coff, ccur, N);
  csr_fill_k<<<(E + 255) / 256, 256, 0, stream>>>(row, col, E, ccur, crows);

  // conv1
  gemm_scale_k<false><<<N / 32, 256, 0, stream>>>(x, W1, dinv, bufA);
  spmm_k<<<N / 4, 256, 0, stream>>>(bufA, coff, crows, dinv, b1, bufB);
  // conv2 (relu fused on GEMM input load)
  gemm_scale_k<true><<<N / 32, 256, 0, stream>>>(bufB, W2, dinv, bufA);
  spmm_k<<<N / 4, 256, 0, stream>>>(bufA, coff, crows, dinv, b2, bufB);

  // readout (relu fused into pool)
  pool_k<<<NGRAPHS * 16, 128, 0, stream>>>(bufB, batch, gfeat);
  mlp_k<<<NGRAPHS, 128, 0, stream>>>(gfeat, batch, Wl1, bl1, Wl2, bl2, Wl3, bl3, out);
}

// Round 2
// 619.282 us; speedup vs baseline: 1.4272x; 1.4272x over previous
//
#include <hip/hip_runtime.h>
#include <hip/hip_bf16.h>

#define NNODES 100000
#define FHID 128
#define NGRAPHS 64
#define NCLASSES 10

__device__ __forceinline__ int lbound(const int* __restrict__ a, int n, int key) {
  int lo = 0, hi = n;
  while (lo < hi) { int mid = (lo + hi) >> 1; if (a[mid] < key) lo = mid + 1; else hi = mid; }
  return lo;
}

// ---- degree histogram (in-degree over col, excluding self loops) ----
__global__ void count_deg_k(const int* __restrict__ col, int E, int* __restrict__ deg) {
  int e = blockIdx.x * 256 + threadIdx.x;
  if (e < E) atomicAdd(&deg[col[e]], 1);
}

// ---- two-level scan, stage 1: per-block (256-wide) sums of deg ----
__global__ __launch_bounds__(256) void bsum_k(const int* __restrict__ deg, int N,
                                              int* __restrict__ bsum) {
  __shared__ int red[4];
  int t = threadIdx.x;
  int i = blockIdx.x * 256 + t;
  int v = (i < N) ? deg[i] : 0;
  #pragma unroll
  for (int off = 32; off > 0; off >>= 1) v += __shfl_down(v, off, 64);
  if ((t & 63) == 0) red[t >> 6] = v;
  __syncthreads();
  if (t == 0) bsum[blockIdx.x] = red[0] + red[1] + red[2] + red[3];
}

// ---- stage 2: single small block exclusive-scans the block sums ----
__global__ __launch_bounds__(512) void bscan_k(const int* __restrict__ bsum, int NB,
                                               int* __restrict__ bpre) {
  __shared__ int s[512];
  int t = threadIdx.x;
  int v = (t < NB) ? bsum[t] : 0;
  s[t] = v;
  __syncthreads();
  #pragma unroll
  for (int off = 1; off < 512; off <<= 1) {
    int u = (t >= off) ? s[t - off] : 0;
    __syncthreads();
    s[t] += u;
    __syncthreads();
  }
  if (t < NB) bpre[t] = s[t] - v;   // exclusive
}

// ---- stage 3: per-block local scan + prefix -> coff/ccur/dinv ----
__global__ __launch_bounds__(256) void scan_out_k(const int* __restrict__ deg,
    const int* __restrict__ bpre, float* __restrict__ dinv,
    int* __restrict__ coff, int* __restrict__ ccur, int N) {
  __shared__ int s[256];
  int t = threadIdx.x;
  int i = blockIdx.x * 256 + t;
  int d = (i < N) ? deg[i] : 0;
  s[t] = d;
  __syncthreads();
  #pragma unroll
  for (int off = 1; off < 256; off <<= 1) {
    int u = (t >= off) ? s[t - off] : 0;
    __syncthreads();
    s[t] += u;
    __syncthreads();
  }
  int incl = s[t];
  int base = bpre[blockIdx.x];
  if (i < N) {
    int excl = base + incl - d;
    coff[i] = excl;
    ccur[i] = excl;
    dinv[i] = rsqrtf((float)(d + 1));   // +1 = self loop
  }
  if (i == N - 1) coff[N] = base + incl;  // total == E
}

// ---- CSR fill: for each edge store its source row under target col ----
__global__ void csr_fill_k(const int* __restrict__ row, const int* __restrict__ col, int E,
                           int* __restrict__ ccur, int* __restrict__ rows) {
  int e = blockIdx.x * 256 + threadIdx.x;
  if (e < E) {
    int p = atomicAdd(&ccur[col[e]], 1);
    rows[p] = row[e];
  }
}

// ---- hs = (act(in) @ W) * dinv[node]  ; 32-node tile, 4n x 4f per thread ----
template<bool RELU>
__global__ __launch_bounds__(256) void gemm_scale_k(const float* __restrict__ in,
    const float* __restrict__ W, const float* __restrict__ dinv, float* __restrict__ out) {
  __shared__ float Wl[FHID * FHID];     // 64 KB
  __shared__ float xl[32 * FHID];       // 16 KB
  int tid = threadIdx.x;
  const float4* W4 = reinterpret_cast<const float4*>(W);
  float4* Wl4 = reinterpret_cast<float4*>(Wl);
  #pragma unroll
  for (int i = 0; i < 16; ++i) Wl4[tid + i * 256] = W4[tid + i * 256];
  int n0 = blockIdx.x * 32;
  const float4* in4 = reinterpret_cast<const float4*>(in + (size_t)n0 * FHID);
  float4* xl4 = reinterpret_cast<float4*>(xl);
  #pragma unroll
  for (int i = 0; i < 4; ++i) {
    float4 v = in4[tid + i * 256];
    if (RELU) {
      v.x = fmaxf(v.x, 0.f); v.y = fmaxf(v.y, 0.f);
      v.z = fmaxf(v.z, 0.f); v.w = fmaxf(v.w, 0.f);
    }
    xl4[tid + i * 256] = v;
  }
  __syncthreads();
  int tf = tid & 31, tn = tid >> 5;
  const float* x0 = xl + (4 * tn + 0) * FHID;
  const float* x1 = xl + (4 * tn + 1) * FHID;
  const float* x2 = xl + (4 * tn + 2) * FHID;
  const float* x3 = xl + (4 * tn + 3) * FHID;
  float4 a0 = {0,0,0,0}, a1 = {0,0,0,0}, a2 = {0,0,0,0}, a3 = {0,0,0,0};
  #pragma unroll 4
  for (int k = 0; k < FHID; ++k) {
    float4 w = *reinterpret_cast<const float4*>(Wl + k * FHID + 4 * tf);
    float v0 = x0[k], v1 = x1[k], v2 = x2[k], v3 = x3[k];
    a0.x += v0 * w.x; a0.y += v0 * w.y; a0.z += v0 * w.z; a0.w += v0 * w.w;
    a1.x += v1 * w.x; a1.y += v1 * w.y; a1.z += v1 * w.z; a1.w += v1 * w.w;
    a2.x += v2 * w.x; a2.y += v2 * w.y; a2.z += v2 * w.z; a2.w += v2 * w.w;
    a3.x += v3 * w.x; a3.y += v3 * w.y; a3.z += v3 * w.z; a3.w += v3 * w.w;
  }
  int nbase = n0 + 4 * tn;
  float d0 = dinv[nbase + 0], d1 = dinv[nbase + 1], d2 = dinv[nbase + 2], d3 = dinv[nbase + 3];
  float4* o4 = reinterpret_cast<float4*>(out);
  float4 r;
  r.x = a0.x * d0; r.y = a0.y * d0; r.z = a0.z * d0; r.w = a0.w * d0;
  o4[(size_t)(nbase + 0) * 32 + tf] = r;
  r.x = a1.x * d1; r.y = a1.y * d1; r.z = a1.z * d1; r.w = a1.w * d1;
  o4[(size_t)(nbase + 1) * 32 + tf] = r;
  r.x = a2.x * d2; r.y = a2.y * d2; r.z = a2.z * d2; r.w = a2.w * d2;
  o4[(size_t)(nbase + 2) * 32 + tf] = r;
  r.x = a3.x * d3; r.y = a3.y * d3; r.z = a3.z * d3; r.w = a3.w * d3;
  o4[(size_t)(nbase + 3) * 32 + tf] = r;
}

// ---- SpMM gather: out[i] = b + dinv[i]*(hs[i] + sum_{j in in(i)} hs[j]) ----
__global__ __launch_bounds__(256) void spmm_k(const float* __restrict__ hs,
    const int* __restrict__ coff, const int* __restrict__ rows,
    const float* __restrict__ dinv, const float* __restrict__ bias, float* __restrict__ out) {
  int node = blockIdx.x * 4 + (threadIdx.x >> 6);
  int lane = threadIdx.x & 63;
  const float2* h2 = reinterpret_cast<const float2*>(hs);
  float2 acc = h2[(size_t)node * 64 + lane];  // self term hs[i]
  float2 acc2 = {0.f, 0.f};
  int s = coff[node], e = coff[node + 1];
  int p = s;
  for (; p + 2 <= e; p += 2) {
    int j0 = rows[p], j1 = rows[p + 1];
    float2 v0 = h2[(size_t)j0 * 64 + lane];
    float2 v1 = h2[(size_t)j1 * 64 + lane];
    acc.x += v0.x; acc.y += v0.y;
    acc2.x += v1.x; acc2.y += v1.y;
  }
  if (p < e) {
    int j = rows[p];
    float2 v = h2[(size_t)j * 64 + lane];
    acc.x += v.x; acc.y += v.y;
  }
  float di = dinv[node];
  float2 b = reinterpret_cast<const float2*>(bias)[lane];
  float2 o;
  o.x = b.x + di * (acc.x + acc2.x);
  o.y = b.y + di * (acc.y + acc2.y);
  reinterpret_cast<float2*>(out)[(size_t)node * 64 + lane] = o;
}

// ---- pooling: per (graph, chunk) block; relu applied here; max via int atomics ----
__global__ __launch_bounds__(128) void pool_k(const float* __restrict__ h,
    const int* __restrict__ batch, float* __restrict__ gfeat) {
  int g = blockIdx.x >> 4;
  int c = blockIdx.x & 15;
  int f = threadIdx.x;
  int lo = lbound(batch, NNODES, g);
  int hi = lbound(batch, NNODES, g + 1);
  int len = hi - lo;
  int cs = lo + ((len * c) >> 4);
  int ce = lo + ((len * (c + 1)) >> 4);
  float mx = 0.f, sm = 0.f;
  for (int n = cs; n < ce; ++n) {
    float v = fmaxf(h[(size_t)n * FHID + f], 0.f);
    mx = fmaxf(mx, v);
    sm += v;
  }
  // relu output >= 0, so int-compare == float-compare; init 0 matches empty->0 semantics
  atomicMax(reinterpret_cast<int*>(&gfeat[g * 256 + f]), __float_as_int(mx));
  atomicAdd(&gfeat[g * 256 + 128 + f], sm);
}

// ---- MLP head + log_softmax: one block per graph ----
__global__ __launch_bounds__(128) void mlp_k(const float* __restrict__ gfeat,
    const int* __restrict__ batch,
    const float* __restrict__ Wl1, const float* __restrict__ bl1,
    const float* __restrict__ Wl2, const float* __restrict__ bl2,
    const float* __restrict__ Wl3, const float* __restrict__ bl3,
    float* __restrict__ out) {
  int g = blockIdx.x;
  int t = threadIdx.x;
  __shared__ float gv[256];
  __shared__ float a1[128];
  __shared__ float a2[64];
  __shared__ float z[NCLASSES];
  __shared__ float red[2];
  int lo = lbound(batch, NNODES, g);
  int hi = lbound(batch, NNODES, g + 1);
  float invc = 1.0f / (float)max(hi - lo, 1);
  gv[t] = gfeat[g * 256 + t];                       // gmp (bits written by atomicMax)
  gv[128 + t] = gfeat[g * 256 + 128 + t] * invc;    // gap = sum/cnt
  __syncthreads();
  float s = bl1[t];
  for (int k = 0; k < 256; ++k) s += gv[k] * Wl1[k * 128 + t];
  a1[t] = fmaxf(s, 0.f);
  __syncthreads();
  if (t < 64) {
    float s2 = bl2[t];
    for (int k = 0; k < 128; ++k) s2 += a1[k] * Wl2[k * 64 + t];
    a2[t] = fmaxf(s2, 0.f);
  }
  __syncthreads();
  if (t < NCLASSES) {
    float s3 = bl3[t];
    for (int k = 0; k < 64; ++k) s3 += a2[k] * Wl3[k * NCLASSES + t];
    z[t] = s3;
  }
  __syncthreads();
  if (t == 0) {
    float m = z[0];
    for (int i = 1; i < NCLASSES; ++i) m = fmaxf(m, z[i]);
    float sum = 0.f;
    for (int i = 0; i < NCLASSES; ++i) sum += expf(z[i] - m);
    red[0] = m; red[1] = logf(sum);
  }
  __syncthreads();
  if (t < NCLASSES) out[g * NCLASSES + t] = z[t] - red[0] - red[1];
}

extern "C" void kernel_launch(void* const* d_in, const int* in_sizes, int n_in,
                              void* d_out, int out_size, void* d_ws, size_t ws_size,
                              hipStream_t stream) {
  const float* x     = (const float*)d_in[0];
  const int*   ei    = (const int*)d_in[1];
  const int*   batch = (const int*)d_in[2];
  const float* W1    = (const float*)d_in[3];
  const float* b1    = (const float*)d_in[4];
  const float* W2    = (const float*)d_in[5];
  const float* b2    = (const float*)d_in[6];
  const float* Wl1   = (const float*)d_in[7];
  const float* bl1   = (const float*)d_in[8];
  const float* Wl2   = (const float*)d_in[9];
  const float* bl2   = (const float*)d_in[10];
  const float* Wl3   = (const float*)d_in[11];
  const float* bl3   = (const float*)d_in[12];
  float* out = (float*)d_out;

  const int N = NNODES;
  const int E = in_sizes[1] / 2;
  const int* row = ei;       // sources
  const int* col = ei + E;   // targets
  const int NB = (N + 255) / 256;  // 391

  char* ws = (char*)d_ws;
  size_t off = 0;
  auto alloc = [&](size_t bytes) {
    size_t cur = off;
    off += (bytes + 255) & ~(size_t)255;
    return (void*)(ws + cur);
  };
  int*   deg   = (int*)alloc((size_t)N * 4);
  float* dinv  = (float*)alloc((size_t)N * 4);
  int*   coff  = (int*)alloc((size_t)(N + 1) * 4);
  int*   ccur  = (int*)alloc((size_t)N * 4);
  int*   bsum  = (int*)alloc((size_t)NB * 4);
  int*   bpre  = (int*)alloc((size_t)NB * 4);
  int*   crows = (int*)alloc((size_t)E * 4);
  float* bufA  = (float*)alloc((size_t)N * FHID * 4);   // hs (scaled transformed feats)
  float* bufB  = (float*)alloc((size_t)N * FHID * 4);   // conv outputs (pre-relu)
  float* gfeat = (float*)alloc((size_t)NGRAPHS * 256 * 4);

  hipMemsetAsync(deg, 0, (size_t)N * 4, stream);
  hipMemsetAsync(gfeat, 0, (size_t)NGRAPHS * 256 * 4, stream);

  count_deg_k<<<(E + 255) / 256, 256, 0, stream>>>(col, E, deg);
  bsum_k<<<NB, 256, 0, stream>>>(deg, N, bsum);
  bscan_k<<<1, 512, 0, stream>>>(bsum, NB, bpre);
  scan_out_k<<<NB, 256, 0, stream>>>(deg, bpre, dinv, coff, ccur, N);
  csr_fill_k<<<(E + 255) / 256, 256, 0, stream>>>(row, col, E, ccur, crows);

  // conv1
  gemm_scale_k<false><<<N / 32, 256, 0, stream>>>(x, W1, dinv, bufA);
  spmm_k<<<N / 4, 256, 0, stream>>>(bufA, coff, crows, dinv, b1, bufB);
  // conv2 (relu fused on GEMM input load)
  gemm_scale_k<true><<<N / 32, 256, 0, stream>>>(bufB, W2, dinv, bufA);
  spmm_k<<<N / 4, 256, 0, stream>>>(bufA, coff, crows, dinv, b2, bufB);

  // readout (relu fused into pool)
  pool_k<<<NGRAPHS * 16, 128, 0, stream>>>(bufB, batch, gfeat);
  mlp_k<<<NGRAPHS, 128, 0, stream>>>(gfeat, batch, Wl1, bl1, Wl2, bl2, Wl3, bl3, out);
}

// Round 3
// 476.260 us; speedup vs baseline: 1.8558x; 1.3003x over previous
//
#include <hip/hip_runtime.h>
#include <hip/hip_bf16.h>

#define NNODES 100000
#define FHID 128
#define NGRAPHS 64
#define NCLASSES 10
#define NBUCK 391          // ceil(NNODES/256)
#define CHUNK 6144
#define ORDCAP 5120        // bucket mean 4092, sigma ~64; +16 sigma

__device__ __forceinline__ int lbound(const int* __restrict__ a, int n, int key) {
  int lo = 0, hi = n;
  while (lo < hi) { int mid = (lo + hi) >> 1; if (a[mid] < key) lo = mid + 1; else hi = mid; }
  return lo;
}

// ---- stage 1: coarse histogram over 391 buckets (col>>8), LDS-aggregated ----
__global__ __launch_bounds__(256) void hist_coarse_k(const int* __restrict__ col, int E,
                                                     int* __restrict__ gcnt) {
  __shared__ int h[NBUCK];
  int t = threadIdx.x;
  for (int i = t; i < NBUCK; i += 256) h[i] = 0;
  __syncthreads();
  int s = blockIdx.x * CHUNK;
  int e2 = min(s + CHUNK, E);
  for (int e = s + t; e < e2; e += 256) atomicAdd(&h[col[e] >> 8], 1);
  __syncthreads();
  for (int i = t; i < NBUCK; i += 256) if (h[i]) atomicAdd(&gcnt[i], h[i]);
}

// ---- stage 2: scan bucket counts -> bases + cursors; coff[N]=E ----
__global__ __launch_bounds__(512) void bucket_scan_k(const int* __restrict__ gcnt,
    int* __restrict__ bboff, int* __restrict__ gcur, int* __restrict__ coff) {
  __shared__ int s[512];
  int t = threadIdx.x;
  int v = (t < NBUCK) ? gcnt[t] : 0;
  s[t] = v;
  __syncthreads();
  #pragma unroll
  for (int off = 1; off < 512; off <<= 1) {
    int u = (t >= off) ? s[t - off] : 0;
    __syncthreads();
    s[t] += u;
    __syncthreads();
  }
  if (t < NBUCK) { int ex = s[t] - v; bboff[t] = ex; gcur[t] = ex; }
  if (t == 511) { bboff[NBUCK] = s[511]; coff[NNODES] = s[511]; }
}

// ---- stage 3: partition edges into bucket runs (block-local reservations) ----
__global__ __launch_bounds__(256) void partition_k(const int* __restrict__ row,
    const int* __restrict__ col, int E, int* __restrict__ gcur, int2* __restrict__ part) {
  __shared__ int h[NBUCK];
  __shared__ int gb[NBUCK];
  __shared__ int lc[NBUCK];
  int t = threadIdx.x;
  for (int i = t; i < NBUCK; i += 256) h[i] = 0;
  __syncthreads();
  int s = blockIdx.x * CHUNK;
  int e2 = min(s + CHUNK, E);
  for (int e = s + t; e < e2; e += 256) atomicAdd(&h[col[e] >> 8], 1);
  __syncthreads();
  for (int i = t; i < NBUCK; i += 256) {
    if (h[i]) gb[i] = atomicAdd(&gcur[i], h[i]);
    lc[i] = 0;
  }
  __syncthreads();
  for (int e = s + t; e < e2; e += 256) {
    int r = row[e], c = col[e];
    int b = c >> 8;
    int o = atomicAdd(&lc[b], 1);
    part[gb[b] + o] = make_int2(r, c);
  }
}

// ---- stage 4: per-bucket fine CSR: degrees, dinv, coff, ordered rows ----
__global__ __launch_bounds__(256) void fine_csr_k(const int2* __restrict__ part,
    const int* __restrict__ bboff, int* __restrict__ rows, int* __restrict__ coff,
    float* __restrict__ dinv) {
  __shared__ int cnt[256];
  __shared__ int pre[256];
  __shared__ int lc[256];
  __shared__ int ordered[ORDCAP];
  int b = blockIdx.x;
  int base = bboff[b];
  int nE = bboff[b + 1] - base;
  if (nE > ORDCAP) nE = ORDCAP;  // statistically impossible; guards LDS OOB
  int t = threadIdx.x;
  cnt[t] = 0;
  __syncthreads();
  for (int k = t; k < nE; k += 256) atomicAdd(&cnt[part[base + k].y & 255], 1);
  __syncthreads();
  pre[t] = cnt[t];
  __syncthreads();
  #pragma unroll
  for (int off = 1; off < 256; off <<= 1) {
    int u = (t >= off) ? pre[t - off] : 0;
    __syncthreads();
    pre[t] += u;
    __syncthreads();
  }
  int node = (b << 8) + t;
  if (node < NNODES) {
    coff[node] = base + pre[t] - cnt[t];
    dinv[node] = rsqrtf((float)(cnt[t] + 1));   // +1 = self loop
  }
  lc[t] = 0;
  __syncthreads();
  for (int k = t; k < nE; k += 256) {
    int2 v = part[base + k];
    int ln = v.y & 255;
    int pos = (pre[ln] - cnt[ln]) + atomicAdd(&lc[ln], 1);
    ordered[pos] = v.x;
  }
  __syncthreads();
  for (int k = t; k < nE; k += 256) rows[base + k] = ordered[k];
}

// ---- hs = (act(in) @ W) * dinv[node]  ; 32-node tile, 4n x 4f per thread ----
template<bool RELU>
__global__ __launch_bounds__(256) void gemm_scale_k(const float* __restrict__ in,
    const float* __restrict__ W, const float* __restrict__ dinv, float* __restrict__ out) {
  __shared__ float Wl[FHID * FHID];     // 64 KB
  __shared__ float xl[32 * FHID];       // 16 KB
  int tid = threadIdx.x;
  const float4* W4 = reinterpret_cast<const float4*>(W);
  float4* Wl4 = reinterpret_cast<float4*>(Wl);
  #pragma unroll
  for (int i = 0; i < 16; ++i) Wl4[tid + i * 256] = W4[tid + i * 256];
  int n0 = blockIdx.x * 32;
  const float4* in4 = reinterpret_cast<const float4*>(in + (size_t)n0 * FHID);
  float4* xl4 = reinterpret_cast<float4*>(xl);
  #pragma unroll
  for (int i = 0; i < 4; ++i) {
    float4 v = in4[tid + i * 256];
    if (RELU) {
      v.x = fmaxf(v.x, 0.f); v.y = fmaxf(v.y, 0.f);
      v.z = fmaxf(v.z, 0.f); v.w = fmaxf(v.w, 0.f);
    }
    xl4[tid + i * 256] = v;
  }
  __syncthreads();
  int tf = tid & 31, tn = tid >> 5;
  const float* x0 = xl + (4 * tn + 0) * FHID;
  const float* x1 = xl + (4 * tn + 1) * FHID;
  const float* x2 = xl + (4 * tn + 2) * FHID;
  const float* x3 = xl + (4 * tn + 3) * FHID;
  float4 a0 = {0,0,0,0}, a1 = {0,0,0,0}, a2 = {0,0,0,0}, a3 = {0,0,0,0};
  #pragma unroll 4
  for (int k = 0; k < FHID; ++k) {
    float4 w = *reinterpret_cast<const float4*>(Wl + k * FHID + 4 * tf);
    float v0 = x0[k], v1 = x1[k], v2 = x2[k], v3 = x3[k];
    a0.x += v0 * w.x; a0.y += v0 * w.y; a0.z += v0 * w.z; a0.w += v0 * w.w;
    a1.x += v1 * w.x; a1.y += v1 * w.y; a1.z += v1 * w.z; a1.w += v1 * w.w;
    a2.x += v2 * w.x; a2.y += v2 * w.y; a2.z += v2 * w.z; a2.w += v2 * w.w;
    a3.x += v3 * w.x; a3.y += v3 * w.y; a3.z += v3 * w.z; a3.w += v3 * w.w;
  }
  int nbase = n0 + 4 * tn;
  float d0 = dinv[nbase + 0], d1 = dinv[nbase + 1], d2 = dinv[nbase + 2], d3 = dinv[nbase + 3];
  float4* o4 = reinterpret_cast<float4*>(out);
  float4 r;
  r.x = a0.x * d0; r.y = a0.y * d0; r.z = a0.z * d0; r.w = a0.w * d0;
  o4[(size_t)(nbase + 0) * 32 + tf] = r;
  r.x = a1.x * d1; r.y = a1.y * d1; r.z = a1.z * d1; r.w = a1.w * d1;
  o4[(size_t)(nbase + 1) * 32 + tf] = r;
  r.x = a2.x * d2; r.y = a2.y * d2; r.z = a2.z * d2; r.w = a2.w * d2;
  o4[(size_t)(nbase + 2) * 32 + tf] = r;
  r.x = a3.x * d3; r.y = a3.y * d3; r.z = a3.z * d3; r.w = a3.w * d3;
  o4[(size_t)(nbase + 3) * 32 + tf] = r;
}

// ---- SpMM gather: out[i] = b + dinv[i]*(hs[i] + sum_{j in in(i)} hs[j]) ----
__global__ __launch_bounds__(256) void spmm_k(const float* __restrict__ hs,
    const int* __restrict__ coff, const int* __restrict__ rows,
    const float* __restrict__ dinv, const float* __restrict__ bias, float* __restrict__ out) {
  int node = blockIdx.x * 4 + (threadIdx.x >> 6);
  int lane = threadIdx.x & 63;
  const float2* h2 = reinterpret_cast<const float2*>(hs);
  float2 acc = h2[(size_t)node * 64 + lane];  // self term hs[i]
  float2 acc2 = {0.f, 0.f};
  int s = coff[node], e = coff[node + 1];
  int p = s;
  for (; p + 2 <= e; p += 2) {
    int j0 = rows[p], j1 = rows[p + 1];
    float2 v0 = h2[(size_t)j0 * 64 + lane];
    float2 v1 = h2[(size_t)j1 * 64 + lane];
    acc.x += v0.x; acc.y += v0.y;
    acc2.x += v1.x; acc2.y += v1.y;
  }
  if (p < e) {
    int j = rows[p];
    float2 v = h2[(size_t)j * 64 + lane];
    acc.x += v.x; acc.y += v.y;
  }
  float di = dinv[node];
  float2 b = reinterpret_cast<const float2*>(bias)[lane];
  float2 o;
  o.x = b.x + di * (acc.x + acc2.x);
  o.y = b.y + di * (acc.y + acc2.y);
  reinterpret_cast<float2*>(out)[(size_t)node * 64 + lane] = o;
}

// ---- pooling: per (graph, chunk) block; relu applied here; max via int atomics ----
__global__ __launch_bounds__(128) void pool_k(const float* __restrict__ h,
    const int* __restrict__ batch, float* __restrict__ gfeat) {
  int g = blockIdx.x >> 4;
  int c = blockIdx.x & 15;
  int f = threadIdx.x;
  int lo = lbound(batch, NNODES, g);
  int hi = lbound(batch, NNODES, g + 1);
  int len = hi - lo;
  int cs = lo + ((len * c) >> 4);
  int ce = lo + ((len * (c + 1)) >> 4);
  float mx = 0.f, sm = 0.f;
  for (int n = cs; n < ce; ++n) {
    float v = fmaxf(h[(size_t)n * FHID + f], 0.f);
    mx = fmaxf(mx, v);
    sm += v;
  }
  // relu output >= 0, so int-compare == float-compare; init 0 matches empty->0 semantics
  atomicMax(reinterpret_cast<int*>(&gfeat[g * 256 + f]), __float_as_int(mx));
  atomicAdd(&gfeat[g * 256 + 128 + f], sm);
}

// ---- MLP head + log_softmax: one block per graph ----
__global__ __launch_bounds__(128) void mlp_k(const float* __restrict__ gfeat,
    const int* __restrict__ batch,
    const float* __restrict__ Wl1, const float* __restrict__ bl1,
    const float* __restrict__ Wl2, const float* __restrict__ bl2,
    const float* __restrict__ Wl3, const float* __restrict__ bl3,
    float* __restrict__ out) {
  int g = blockIdx.x;
  int t = threadIdx.x;
  __shared__ float gv[256];
  __shared__ float a1[128];
  __shared__ float a2[64];
  __shared__ float z[NCLASSES];
  __shared__ float red[2];
  int lo = lbound(batch, NNODES, g);
  int hi = lbound(batch, NNODES, g + 1);
  float invc = 1.0f / (float)max(hi - lo, 1);
  gv[t] = gfeat[g * 256 + t];                       // gmp (bits written by atomicMax)
  gv[128 + t] = gfeat[g * 256 + 128 + t] * invc;    // gap = sum/cnt
  __syncthreads();
  float s = bl1[t];
  for (int k = 0; k < 256; ++k) s += gv[k] * Wl1[k * 128 + t];
  a1[t] = fmaxf(s, 0.f);
  __syncthreads();
  if (t < 64) {
    float s2 = bl2[t];
    for (int k = 0; k < 128; ++k) s2 += a1[k] * Wl2[k * 64 + t];
    a2[t] = fmaxf(s2, 0.f);
  }
  __syncthreads();
  if (t < NCLASSES) {
    float s3 = bl3[t];
    for (int k = 0; k < 64; ++k) s3 += a2[k] * Wl3[k * NCLASSES + t];
    z[t] = s3;
  }
  __syncthreads();
  if (t == 0) {
    float m = z[0];
    for (int i = 1; i < NCLASSES; ++i) m = fmaxf(m, z[i]);
    float sum = 0.f;
    for (int i = 0; i < NCLASSES; ++i) sum += expf(z[i] - m);
    red[0] = m; red[1] = logf(sum);
  }
  __syncthreads();
  if (t < NCLASSES) out[g * NCLASSES + t] = z[t] - red[0] - red[1];
}

extern "C" void kernel_launch(void* const* d_in, const int* in_sizes, int n_in,
                              void* d_out, int out_size, void* d_ws, size_t ws_size,
                              hipStream_t stream) {
  const float* x     = (const float*)d_in[0];
  const int*   ei    = (const int*)d_in[1];
  const int*   batch = (const int*)d_in[2];
  const float* W1    = (const float*)d_in[3];
  const float* b1    = (const float*)d_in[4];
  const float* W2    = (const float*)d_in[5];
  const float* b2    = (const float*)d_in[6];
  const float* Wl1   = (const float*)d_in[7];
  const float* bl1   = (const float*)d_in[8];
  const float* Wl2   = (const float*)d_in[9];
  const float* bl2   = (const float*)d_in[10];
  const float* Wl3   = (const float*)d_in[11];
  const float* bl3   = (const float*)d_in[12];
  float* out = (float*)d_out;

  const int N = NNODES;
  const int E = in_sizes[1] / 2;
  const int* row = ei;       // sources
  const int* col = ei + E;   // targets
  const int NBLK = (E + CHUNK - 1) / CHUNK;  // 261

  char* ws = (char*)d_ws;
  size_t off = 0;
  auto alloc = [&](size_t bytes) {
    size_t cur = off;
    off += (bytes + 255) & ~(size_t)255;
    return (void*)(ws + cur);
  };
  float* dinv  = (float*)alloc((size_t)N * 4);
  int*   coff  = (int*)alloc((size_t)(N + 1) * 4);
  int*   gcnt  = (int*)alloc((size_t)NBUCK * 4);
  int*   gcur  = (int*)alloc((size_t)NBUCK * 4);
  int*   bboff = (int*)alloc((size_t)(NBUCK + 1) * 4);
  int*   crows = (int*)alloc((size_t)E * 4);
  float* bufA  = (float*)alloc((size_t)N * FHID * 4);   // hs (scaled transformed feats)
  float* bufB  = (float*)alloc((size_t)N * FHID * 4);   // conv outputs (pre-relu)
  float* gfeat = (float*)alloc((size_t)NGRAPHS * 256 * 4);
  int2*  part  = (int2*)bufB;   // alias: part dead before bufB first written

  hipMemsetAsync(gcnt, 0, (size_t)NBUCK * 4, stream);
  hipMemsetAsync(gfeat, 0, (size_t)NGRAPHS * 256 * 4, stream);

  // CSR build (bucketed, locality-aware)
  hist_coarse_k<<<NBLK, 256, 0, stream>>>(col, E, gcnt);
  bucket_scan_k<<<1, 512, 0, stream>>>(gcnt, bboff, gcur, coff);
  partition_k<<<NBLK, 256, 0, stream>>>(row, col, E, gcur, part);
  fine_csr_k<<<NBUCK, 256, 0, stream>>>(part, bboff, crows, coff, dinv);

  // conv1
  gemm_scale_k<false><<<N / 32, 256, 0, stream>>>(x, W1, dinv, bufA);
  spmm_k<<<N / 4, 256, 0, stream>>>(bufA, coff, crows, dinv, b1, bufB);
  // conv2 (relu fused on GEMM input load)
  gemm_scale_k<true><<<N / 32, 256, 0, stream>>>(bufB, W2, dinv, bufA);
  spmm_k<<<N / 4, 256, 0, stream>>>(bufA, coff, crows, dinv, b2, bufB);

  // readout (relu fused into pool)
  pool_k<<<NGRAPHS * 16, 128, 0, stream>>>(bufB, batch, gfeat);
  mlp_k<<<NGRAPHS, 128, 0, stream>>>(gfeat, batch, Wl1, bl1, Wl2, bl2, Wl3, bl3, out);
}

// Round 4
// 377.787 us; speedup vs baseline: 2.3396x; 1.2607x over previous
//
#include <hip/hip_runtime.h>
#include <hip/hip_bf16.h>

#define NNODES 100000
#define FHID 128
#define NGRAPHS 64
#define NCLASSES 10
#define NBUCK 391          // ceil(NNODES/256)
#define CHUNK 6144
#define ORDCAP 5120        // bucket mean 4092, sigma ~64; +16 sigma

__device__ __forceinline__ int lbound(const int* __restrict__ a, int n, int key) {
  int lo = 0, hi = n;
  while (lo < hi) { int mid = (lo + hi) >> 1; if (a[mid] < key) lo = mid + 1; else hi = mid; }
  return lo;
}

__device__ __forceinline__ unsigned pack_bf16(float a, float b) {
  unsigned ua = __float_as_uint(a), ub = __float_as_uint(b);
  ua = (ua + 0x7fffu + ((ua >> 16) & 1u)) >> 16;       // RTNE
  ub = (ub + 0x7fffu + ((ub >> 16) & 1u)) >> 16;
  return ua | (ub << 16);
}

// ---- stage 1: coarse histogram over 391 buckets (col>>8), LDS-aggregated ----
__global__ __launch_bounds__(256) void hist_coarse_k(const int* __restrict__ col, int E,
                                                     int* __restrict__ gcnt) {
  __shared__ int h[NBUCK];
  int t = threadIdx.x;
  for (int i = t; i < NBUCK; i += 256) h[i] = 0;
  __syncthreads();
  int s = blockIdx.x * CHUNK;
  int e2 = min(s + CHUNK, E);
  for (int e = s + t; e < e2; e += 256) atomicAdd(&h[col[e] >> 8], 1);
  __syncthreads();
  for (int i = t; i < NBUCK; i += 256) if (h[i]) atomicAdd(&gcnt[i], h[i]);
}

// ---- stage 2: scan bucket counts -> bases + cursors; coff[N]=E ----
__global__ __launch_bounds__(512) void bucket_scan_k(const int* __restrict__ gcnt,
    int* __restrict__ bboff, int* __restrict__ gcur, int* __restrict__ coff) {
  __shared__ int s[512];
  int t = threadIdx.x;
  int v = (t < NBUCK) ? gcnt[t] : 0;
  s[t] = v;
  __syncthreads();
  #pragma unroll
  for (int off = 1; off < 512; off <<= 1) {
    int u = (t >= off) ? s[t - off] : 0;
    __syncthreads();
    s[t] += u;
    __syncthreads();
  }
  if (t < NBUCK) { int ex = s[t] - v; bboff[t] = ex; gcur[t] = ex; }
  if (t == 511) { bboff[NBUCK] = s[511]; coff[NNODES] = s[511]; }
}

// ---- stage 3: partition edges into bucket runs (block-local reservations) ----
__global__ __launch_bounds__(256) void partition_k(const int* __restrict__ row,
    const int* __restrict__ col, int E, int* __restrict__ gcur, int2* __restrict__ part) {
  __shared__ int h[NBUCK];
  __shared__ int gb[NBUCK];
  __shared__ int lc[NBUCK];
  int t = threadIdx.x;
  for (int i = t; i < NBUCK; i += 256) h[i] = 0;
  __syncthreads();
  int s = blockIdx.x * CHUNK;
  int e2 = min(s + CHUNK, E);
  for (int e = s + t; e < e2; e += 256) atomicAdd(&h[col[e] >> 8], 1);
  __syncthreads();
  for (int i = t; i < NBUCK; i += 256) {
    if (h[i]) gb[i] = atomicAdd(&gcur[i], h[i]);
    lc[i] = 0;
  }
  __syncthreads();
  for (int e = s + t; e < e2; e += 256) {
    int r = row[e], c = col[e];
    int b = c >> 8;
    int o = atomicAdd(&lc[b], 1);
    part[gb[b] + o] = make_int2(r, c);
  }
}

// ---- stage 4: per-bucket fine CSR: degrees, dinv, coff, ordered rows ----
__global__ __launch_bounds__(256) void fine_csr_k(const int2* __restrict__ part,
    const int* __restrict__ bboff, int* __restrict__ rows, int* __restrict__ coff,
    float* __restrict__ dinv) {
  __shared__ int cnt[256];
  __shared__ int pre[256];
  __shared__ int lc[256];
  __shared__ int ordered[ORDCAP];
  int b = blockIdx.x;
  int base = bboff[b];
  int nE = bboff[b + 1] - base;
  if (nE > ORDCAP) nE = ORDCAP;  // statistically impossible; guards LDS OOB
  int t = threadIdx.x;
  cnt[t] = 0;
  __syncthreads();
  for (int k = t; k < nE; k += 256) atomicAdd(&cnt[part[base + k].y & 255], 1);
  __syncthreads();
  pre[t] = cnt[t];
  __syncthreads();
  #pragma unroll
  for (int off = 1; off < 256; off <<= 1) {
    int u = (t >= off) ? pre[t - off] : 0;
    __syncthreads();
    pre[t] += u;
    __syncthreads();
  }
  int node = (b << 8) + t;
  if (node < NNODES) {
    coff[node] = base + pre[t] - cnt[t];
    dinv[node] = rsqrtf((float)(cnt[t] + 1));   // +1 = self loop
  }
  lc[t] = 0;
  __syncthreads();
  for (int k = t; k < nE; k += 256) {
    int2 v = part[base + k];
    int ln = v.y & 255;
    int pos = (pre[ln] - cnt[ln]) + atomicAdd(&lc[ln], 1);
    ordered[pos] = v.x;
  }
  __syncthreads();
  for (int k = t; k < nE; k += 256) rows[base + k] = ordered[k];
}

// ---- hs = (act(in) @ W) * dinv[node], bf16-packed ; 32-node tile, 4n x 4f/thread ----
template<bool RELU>
__global__ __launch_bounds__(256) void gemm_scale_k(const float* __restrict__ in,
    const float* __restrict__ W, const float* __restrict__ dinv, unsigned* __restrict__ out) {
  __shared__ float Wl[FHID * FHID];     // 64 KB
  __shared__ float xl[32 * FHID];       // 16 KB
  int tid = threadIdx.x;
  const float4* W4 = reinterpret_cast<const float4*>(W);
  float4* Wl4 = reinterpret_cast<float4*>(Wl);
  #pragma unroll
  for (int i = 0; i < 16; ++i) Wl4[tid + i * 256] = W4[tid + i * 256];
  int n0 = blockIdx.x * 32;
  const float4* in4 = reinterpret_cast<const float4*>(in + (size_t)n0 * FHID);
  float4* xl4 = reinterpret_cast<float4*>(xl);
  #pragma unroll
  for (int i = 0; i < 4; ++i) {
    float4 v = in4[tid + i * 256];
    if (RELU) {
      v.x = fmaxf(v.x, 0.f); v.y = fmaxf(v.y, 0.f);
      v.z = fmaxf(v.z, 0.f); v.w = fmaxf(v.w, 0.f);
    }
    xl4[tid + i * 256] = v;
  }
  __syncthreads();
  int tf = tid & 31, tn = tid >> 5;
  const float* x0 = xl + (4 * tn + 0) * FHID;
  const float* x1 = xl + (4 * tn + 1) * FHID;
  const float* x2 = xl + (4 * tn + 2) * FHID;
  const float* x3 = xl + (4 * tn + 3) * FHID;
  float4 a0 = {0,0,0,0}, a1 = {0,0,0,0}, a2 = {0,0,0,0}, a3 = {0,0,0,0};
  #pragma unroll 4
  for (int k = 0; k < FHID; ++k) {
    float4 w = *reinterpret_cast<const float4*>(Wl + k * FHID + 4 * tf);
    float v0 = x0[k], v1 = x1[k], v2 = x2[k], v3 = x3[k];
    a0.x += v0 * w.x; a0.y += v0 * w.y; a0.z += v0 * w.z; a0.w += v0 * w.w;
    a1.x += v1 * w.x; a1.y += v1 * w.y; a1.z += v1 * w.z; a1.w += v1 * w.w;
    a2.x += v2 * w.x; a2.y += v2 * w.y; a2.z += v2 * w.z; a2.w += v2 * w.w;
    a3.x += v3 * w.x; a3.y += v3 * w.y; a3.z += v3 * w.z; a3.w += v3 * w.w;
  }
  int nbase = n0 + 4 * tn;
  float d0 = dinv[nbase + 0], d1 = dinv[nbase + 1], d2 = dinv[nbase + 2], d3 = dinv[nbase + 3];
  uint2* o2 = reinterpret_cast<uint2*>(out);
  o2[(size_t)(nbase + 0) * 32 + tf] = make_uint2(pack_bf16(a0.x * d0, a0.y * d0),
                                                 pack_bf16(a0.z * d0, a0.w * d0));
  o2[(size_t)(nbase + 1) * 32 + tf] = make_uint2(pack_bf16(a1.x * d1, a1.y * d1),
                                                 pack_bf16(a1.z * d1, a1.w * d1));
  o2[(size_t)(nbase + 2) * 32 + tf] = make_uint2(pack_bf16(a2.x * d2, a2.y * d2),
                                                 pack_bf16(a2.z * d2, a2.w * d2));
  o2[(size_t)(nbase + 3) * 32 + tf] = make_uint2(pack_bf16(a3.x * d3, a3.y * d3),
                                                 pack_bf16(a3.z * d3, a3.w * d3));
}

// ---- SpMM gather (bf16 rows): out[i] = b + dinv[i]*(hs[i] + sum_j hs[j]) ----
__global__ __launch_bounds__(256) void spmm_k(const unsigned* __restrict__ hs,
    const int* __restrict__ coff, const int* __restrict__ rows,
    const float* __restrict__ dinv, const float* __restrict__ bias, float* __restrict__ out) {
  int node = blockIdx.x * 4 + (threadIdx.x >> 6);
  int lane = threadIdx.x & 63;
  unsigned su = hs[(size_t)node * 64 + lane];        // self term
  float a0x = __uint_as_float(su << 16), a0y = __uint_as_float(su & 0xffff0000u);
  float a1x = 0.f, a1y = 0.f, a2x = 0.f, a2y = 0.f, a3x = 0.f, a3y = 0.f;
  int s = coff[node], e = coff[node + 1];
  int p = s;
  for (; p + 4 <= e; p += 4) {
    int j0 = rows[p], j1 = rows[p + 1], j2 = rows[p + 2], j3 = rows[p + 3];
    unsigned u0 = hs[(size_t)j0 * 64 + lane];
    unsigned u1 = hs[(size_t)j1 * 64 + lane];
    unsigned u2 = hs[(size_t)j2 * 64 + lane];
    unsigned u3 = hs[(size_t)j3 * 64 + lane];
    a0x += __uint_as_float(u0 << 16); a0y += __uint_as_float(u0 & 0xffff0000u);
    a1x += __uint_as_float(u1 << 16); a1y += __uint_as_float(u1 & 0xffff0000u);
    a2x += __uint_as_float(u2 << 16); a2y += __uint_as_float(u2 & 0xffff0000u);
    a3x += __uint_as_float(u3 << 16); a3y += __uint_as_float(u3 & 0xffff0000u);
  }
  for (; p < e; ++p) {
    int j = rows[p];
    unsigned u = hs[(size_t)j * 64 + lane];
    a1x += __uint_as_float(u << 16); a1y += __uint_as_float(u & 0xffff0000u);
  }
  float di = dinv[node];
  float2 b = reinterpret_cast<const float2*>(bias)[lane];
  float2 o;
  o.x = b.x + di * ((a0x + a1x) + (a2x + a3x));
  o.y = b.y + di * ((a0y + a1y) + (a2y + a3y));
  reinterpret_cast<float2*>(out)[(size_t)node * 64 + lane] = o;
}

// ---- pooling: per (graph, chunk) block; relu applied here; max via int atomics ----
__global__ __launch_bounds__(128) void pool_k(const float* __restrict__ h,
    const int* __restrict__ batch, float* __restrict__ gfeat) {
  int g = blockIdx.x >> 4;
  int c = blockIdx.x & 15;
  int f = threadIdx.x;
  int lo = lbound(batch, NNODES, g);
  int hi = lbound(batch, NNODES, g + 1);
  int len = hi - lo;
  int cs = lo + ((len * c) >> 4);
  int ce = lo + ((len * (c + 1)) >> 4);
  float mx = 0.f, sm = 0.f;
  for (int n = cs; n < ce; ++n) {
    float v = fmaxf(h[(size_t)n * FHID + f], 0.f);
    mx = fmaxf(mx, v);
    sm += v;
  }
  // relu output >= 0, so int-compare == float-compare; init 0 matches empty->0 semantics
  atomicMax(reinterpret_cast<int*>(&gfeat[g * 256 + f]), __float_as_int(mx));
  atomicAdd(&gfeat[g * 256 + 128 + f], sm);
}

// ---- MLP head + log_softmax: one block per graph ----
__global__ __launch_bounds__(128) void mlp_k(const float* __restrict__ gfeat,
    const int* __restrict__ batch,
    const float* __restrict__ Wl1, const float* __restrict__ bl1,
    const float* __restrict__ Wl2, const float* __restrict__ bl2,
    const float* __restrict__ Wl3, const float* __restrict__ bl3,
    float* __restrict__ out) {
  int g = blockIdx.x;
  int t = threadIdx.x;
  __shared__ float gv[256];
  __shared__ float a1[128];
  __shared__ float a2[64];
  __shared__ float z[NCLASSES];
  __shared__ float red[2];
  int lo = lbound(batch, NNODES, g);
  int hi = lbound(batch, NNODES, g + 1);
  float invc = 1.0f / (float)max(hi - lo, 1);
  gv[t] = gfeat[g * 256 + t];                       // gmp (bits written by atomicMax)
  gv[128 + t] = gfeat[g * 256 + 128 + t] * invc;    // gap = sum/cnt
  __syncthreads();
  float s = bl1[t];
  for (int k = 0; k < 256; ++k) s += gv[k] * Wl1[k * 128 + t];
  a1[t] = fmaxf(s, 0.f);
  __syncthreads();
  if (t < 64) {
    float s2 = bl2[t];
    for (int k = 0; k < 128; ++k) s2 += a1[k] * Wl2[k * 64 + t];
    a2[t] = fmaxf(s2, 0.f);
  }
  __syncthreads();
  if (t < NCLASSES) {
    float s3 = bl3[t];
    for (int k = 0; k < 64; ++k) s3 += a2[k] * Wl3[k * NCLASSES + t];
    z[t] = s3;
  }
  __syncthreads();
  if (t == 0) {
    float m = z[0];
    for (int i = 1; i < NCLASSES; ++i) m = fmaxf(m, z[i]);
    float sum = 0.f;
    for (int i = 0; i < NCLASSES; ++i) sum += expf(z[i] - m);
    red[0] = m; red[1] = logf(sum);
  }
  __syncthreads();
  if (t < NCLASSES) out[g * NCLASSES + t] = z[t] - red[0] - red[1];
}

extern "C" void kernel_launch(void* const* d_in, const int* in_sizes, int n_in,
                              void* d_out, int out_size, void* d_ws, size_t ws_size,
                              hipStream_t stream) {
  const float* x     = (const float*)d_in[0];
  const int*   ei    = (const int*)d_in[1];
  const int*   batch = (const int*)d_in[2];
  const float* W1    = (const float*)d_in[3];
  const float* b1    = (const float*)d_in[4];
  const float* W2    = (const float*)d_in[5];
  const float* b2    = (const float*)d_in[6];
  const float* Wl1   = (const float*)d_in[7];
  const float* bl1   = (const float*)d_in[8];
  const float* Wl2   = (const float*)d_in[9];
  const float* bl2   = (const float*)d_in[10];
  const float* Wl3   = (const float*)d_in[11];
  const float* bl3   = (const float*)d_in[12];
  float* out = (float*)d_out;

  const int N = NNODES;
  const int E = in_sizes[1] / 2;
  const int* row = ei;       // sources
  const int* col = ei + E;   // targets
  const int NBLK = (E + CHUNK - 1) / CHUNK;  // 261

  char* ws = (char*)d_ws;
  size_t off = 0;
  auto alloc = [&](size_t bytes) {
    size_t cur = off;
    off += (bytes + 255) & ~(size_t)255;
    return (void*)(ws + cur);
  };
  float*    dinv  = (float*)alloc((size_t)N * 4);
  int*      coff  = (int*)alloc((size_t)(N + 1) * 4);
  int*      gcnt  = (int*)alloc((size_t)NBUCK * 4);
  int*      gcur  = (int*)alloc((size_t)NBUCK * 4);
  int*      bboff = (int*)alloc((size_t)(NBUCK + 1) * 4);
  int*      crows = (int*)alloc((size_t)E * 4);
  unsigned* bufA  = (unsigned*)alloc((size_t)N * 64 * 4);   // hs, bf16-packed (25.6 MB)
  float*    bufB  = (float*)alloc((size_t)N * FHID * 4);    // conv outputs (pre-relu)
  float*    gfeat = (float*)alloc((size_t)NGRAPHS * 256 * 4);
  int2*     part  = (int2*)bufB;   // alias: part dead before bufB first written

  hipMemsetAsync(gcnt, 0, (size_t)NBUCK * 4, stream);
  hipMemsetAsync(gfeat, 0, (size_t)NGRAPHS * 256 * 4, stream);

  // CSR build (bucketed, locality-aware)
  hist_coarse_k<<<NBLK, 256, 0, stream>>>(col, E, gcnt);
  bucket_scan_k<<<1, 512, 0, stream>>>(gcnt, bboff, gcur, coff);
  partition_k<<<NBLK, 256, 0, stream>>>(row, col, E, gcur, part);
  fine_csr_k<<<NBUCK, 256, 0, stream>>>(part, bboff, crows, coff, dinv);

  // conv1
  gemm_scale_k<false><<<N / 32, 256, 0, stream>>>(x, W1, dinv, bufA);
  spmm_k<<<N / 4, 256, 0, stream>>>(bufA, coff, crows, dinv, b1, bufB);
  // conv2 (relu fused on GEMM input load)
  gemm_scale_k<true><<<N / 32, 256, 0, stream>>>(bufB, W2, dinv, bufA);
  spmm_k<<<N / 4, 256, 0, stream>>>(bufA, coff, crows, dinv, b2, bufB);

  // readout (relu fused into pool)
  pool_k<<<NGRAPHS * 16, 128, 0, stream>>>(bufB, batch, gfeat);
  mlp_k<<<NGRAPHS, 128, 0, stream>>>(gfeat, batch, Wl1, bl1, Wl2, bl2, Wl3, bl3, out);
}

// Round 5
// 324.494 us; speedup vs baseline: 2.7238x; 1.1642x over previous
//
#include <hip/hip_runtime.h>
#include <hip/hip_bf16.h>

#define NNODES 100000
#define FHID 128
#define NGRAPHS 64
#define NCLASSES 10
#define NBUCK 391          // ceil(NNODES/256)
#define CHUNK 6144
#define ORDCAP 5120        // bucket mean 4092, sigma ~64; +16 sigma

typedef __attribute__((ext_vector_type(8))) short bf16x8;
typedef __attribute__((ext_vector_type(4))) float f32x4;

__device__ __forceinline__ int lbound(const int* __restrict__ a, int n, int key) {
  int lo = 0, hi = n;
  while (lo < hi) { int mid = (lo + hi) >> 1; if (a[mid] < key) lo = mid + 1; else hi = mid; }
  return lo;
}

__device__ __forceinline__ unsigned rtne16(float f) {
  unsigned u = __float_as_uint(f);
  return (u + 0x7fffu + ((u >> 16) & 1u)) >> 16;   // RTNE to bf16, as u16
}

// relu on two packed bf16 halves of a u32
__device__ __forceinline__ unsigned relu2(unsigned u) {
  if (u & 0x80000000u) u &= 0x0000FFFFu;
  if (u & 0x00008000u) u &= 0xFFFF0000u;
  return u;
}

// ---- stage 1: coarse histogram over 391 buckets (col>>8), LDS-aggregated ----
__global__ __launch_bounds__(256) void hist_coarse_k(const int* __restrict__ col, int E,
                                                     int* __restrict__ gcnt) {
  __shared__ int h[NBUCK];
  int t = threadIdx.x;
  for (int i = t; i < NBUCK; i += 256) h[i] = 0;
  __syncthreads();
  int s = blockIdx.x * CHUNK;
  int e2 = min(s + CHUNK, E);
  for (int e = s + t; e < e2; e += 256) atomicAdd(&h[col[e] >> 8], 1);
  __syncthreads();
  for (int i = t; i < NBUCK; i += 256) if (h[i]) atomicAdd(&gcnt[i], h[i]);
}

// ---- stage 2: scan bucket counts -> bases + cursors; coff[N]=E ----
__global__ __launch_bounds__(512) void bucket_scan_k(const int* __restrict__ gcnt,
    int* __restrict__ bboff, int* __restrict__ gcur, int* __restrict__ coff) {
  __shared__ int s[512];
  int t = threadIdx.x;
  int v = (t < NBUCK) ? gcnt[t] : 0;
  s[t] = v;
  __syncthreads();
  #pragma unroll
  for (int off = 1; off < 512; off <<= 1) {
    int u = (t >= off) ? s[t - off] : 0;
    __syncthreads();
    s[t] += u;
    __syncthreads();
  }
  if (t < NBUCK) { int ex = s[t] - v; bboff[t] = ex; gcur[t] = ex; }
  if (t == 511) { bboff[NBUCK] = s[511]; coff[NNODES] = s[511]; }
}

// ---- stage 3: partition edges into bucket runs (block-local reservations) ----
__global__ __launch_bounds__(256) void partition_k(const int* __restrict__ row,
    const int* __restrict__ col, int E, int* __restrict__ gcur, int2* __restrict__ part) {
  __shared__ int h[NBUCK];
  __shared__ int gb[NBUCK];
  __shared__ int lc[NBUCK];
  int t = threadIdx.x;
  for (int i = t; i < NBUCK; i += 256) h[i] = 0;
  __syncthreads();
  int s = blockIdx.x * CHUNK;
  int e2 = min(s + CHUNK, E);
  for (int e = s + t; e < e2; e += 256) atomicAdd(&h[col[e] >> 8], 1);
  __syncthreads();
  for (int i = t; i < NBUCK; i += 256) {
    if (h[i]) gb[i] = atomicAdd(&gcur[i], h[i]);
    lc[i] = 0;
  }
  __syncthreads();
  for (int e = s + t; e < e2; e += 256) {
    int r = row[e], c = col[e];
    int b = c >> 8;
    int o = atomicAdd(&lc[b], 1);
    part[gb[b] + o] = make_int2(r, c);
  }
}

// ---- stage 4: per-bucket fine CSR: degrees, dinv, coff, ordered rows ----
__global__ __launch_bounds__(256) void fine_csr_k(const int2* __restrict__ part,
    const int* __restrict__ bboff, int* __restrict__ rows, int* __restrict__ coff,
    float* __restrict__ dinv) {
  __shared__ int cnt[256];
  __shared__ int pre[256];
  __shared__ int lc[256];
  __shared__ int ordered[ORDCAP];
  int b = blockIdx.x;
  int base = bboff[b];
  int nE = bboff[b + 1] - base;
  if (nE > ORDCAP) nE = ORDCAP;  // statistically impossible; guards LDS OOB
  int t = threadIdx.x;
  cnt[t] = 0;
  __syncthreads();
  for (int k = t; k < nE; k += 256) atomicAdd(&cnt[part[base + k].y & 255], 1);
  __syncthreads();
  pre[t] = cnt[t];
  __syncthreads();
  #pragma unroll
  for (int off = 1; off < 256; off <<= 1) {
    int u = (t >= off) ? pre[t - off] : 0;
    __syncthreads();
    pre[t] += u;
    __syncthreads();
  }
  int node = (b << 8) + t;
  if (node < NNODES) {
    coff[node] = base + pre[t] - cnt[t];
    dinv[node] = rsqrtf((float)(cnt[t] + 1));   // +1 = self loop
  }
  lc[t] = 0;
  __syncthreads();
  for (int k = t; k < nE; k += 256) {
    int2 v = part[base + k];
    int ln = v.y & 255;
    int pos = (pre[ln] - cnt[ln]) + atomicAdd(&lc[ln], 1);
    ordered[pos] = v.x;
  }
  __syncthreads();
  for (int k = t; k < nE; k += 256) rows[base + k] = ordered[k];
}

// ---- MFMA GEMM: hs[n][f] = bf16( (act(in[n]) @ W)[f] * dinv[n] ) ----
// 64-node x 128-f block, 4 waves x 32 f each, K=128 via 4x mfma_16x16x32_bf16.
// A frag: lane l elem i -> A[l&15][8*(l>>4)+i]; B frag: B[8*(l>>4)+i][l&15]
// D frag: reg r -> D[4*(l>>4)+r][l&15]   (guide §3, m89/m91 verified)
template<int IN_BF16_RELU>
__global__ __launch_bounds__(256) void gemm_mfma_k(const void* __restrict__ in_,
    const float* __restrict__ W, const float* __restrict__ dinv,
    unsigned* __restrict__ hs, int N) {
  __shared__ short sA[64 * 136];    // A bf16 [64 nodes][128 k] stride 136
  __shared__ short sW[128 * 136];   // W^T bf16 [128 f][128 k] stride 136
  __shared__ float sdinv[64];
  int t = threadIdx.x;
  int lane = t & 63;
  int wv = t >> 6;
  int kg = lane >> 4;
  int lr = lane & 15;
  int n0 = blockIdx.x * 64;
  int nn = min(64, N - n0);

  // stage W (f32 row-major [k][f]) -> sW bf16 transposed [f][k]
  {
    const float4* W4 = (const float4*)W;
    #pragma unroll
    for (int i = 0; i < 16; ++i) {
      int idx4 = t + i * 256;              // 4096 float4 total
      float4 v = W4[idx4];
      int k = idx4 >> 5;
      int f0 = (idx4 & 31) << 2;
      sW[(f0 + 0) * 136 + k] = (short)rtne16(v.x);
      sW[(f0 + 1) * 136 + k] = (short)rtne16(v.y);
      sW[(f0 + 2) * 136 + k] = (short)rtne16(v.z);
      sW[(f0 + 3) * 136 + k] = (short)rtne16(v.w);
    }
  }
  // stage A
  if (IN_BF16_RELU) {
    const uint4* in16 = (const uint4*)in_;
    #pragma unroll
    for (int i = 0; i < 4; ++i) {
      int flat = t + i * 256;              // 1024 uint4
      int row = flat >> 4, off = flat & 15;
      uint4 v = make_uint4(0, 0, 0, 0);
      if (row < nn) v = in16[(size_t)(n0 + row) * 16 + off];
      v.x = relu2(v.x); v.y = relu2(v.y); v.z = relu2(v.z); v.w = relu2(v.w);
      *(uint4*)(sA + row * 136 + off * 8) = v;
    }
  } else {
    const float4* in4 = (const float4*)in_;
    #pragma unroll
    for (int i = 0; i < 8; ++i) {
      int idx4 = t + i * 256;              // 2048 float4
      int row = idx4 >> 5, off = idx4 & 31;
      float4 v = make_float4(0.f, 0.f, 0.f, 0.f);
      if (row < nn) v = in4[(size_t)(n0 + row) * 32 + off];
      *(uint2*)(sA + row * 136 + off * 4) = make_uint2(
          rtne16(v.x) | (rtne16(v.y) << 16), rtne16(v.z) | (rtne16(v.w) << 16));
    }
  }
  if (t < 64) sdinv[t] = (t < nn) ? dinv[n0 + t] : 0.f;
  __syncthreads();

  int fbase = wv * 32;
  bf16x8 bfr[2][4];
  #pragma unroll
  for (int ft = 0; ft < 2; ++ft)
    #pragma unroll
    for (int ks = 0; ks < 4; ++ks)
      bfr[ft][ks] = *(const bf16x8*)(sW + (fbase + ft * 16 + lr) * 136 + ks * 32 + kg * 8);

  f32x4 acc[4][2] = {};
  #pragma unroll
  for (int nt = 0; nt < 4; ++nt) {
    bf16x8 afr[4];
    #pragma unroll
    for (int ks = 0; ks < 4; ++ks)
      afr[ks] = *(const bf16x8*)(sA + (nt * 16 + lr) * 136 + ks * 32 + kg * 8);
    #pragma unroll
    for (int ft = 0; ft < 2; ++ft)
      #pragma unroll
      for (int ks = 0; ks < 4; ++ks)
        acc[nt][ft] = __builtin_amdgcn_mfma_f32_16x16x32_bf16(
            afr[ks], bfr[ft][ks], acc[nt][ft], 0, 0, 0);
  }
  __syncthreads();

  // epilogue: scale by dinv, pack bf16 into sA (reuse), then coalesced store
  #pragma unroll
  for (int nt = 0; nt < 4; ++nt) {
    #pragma unroll
    for (int r = 0; r < 4; ++r) {
      int node = nt * 16 + kg * 4 + r;
      float dv = sdinv[node];
      #pragma unroll
      for (int ft = 0; ft < 2; ++ft) {
        int f = fbase + ft * 16 + lr;
        sA[node * 136 + f] = (short)rtne16(acc[nt][ft][r] * dv);
      }
    }
  }
  __syncthreads();
  #pragma unroll
  for (int j = 0; j < 4; ++j) {
    int flat = t * 4 + j;                  // 1024 uint4
    int row = flat >> 4, off = flat & 15;
    if (row < nn)
      ((uint4*)hs)[(size_t)(n0 + row) * 16 + off] = *(const uint4*)(sA + row * 136 + off * 8);
  }
}

// ---- SpMM gather (bf16): h[i] = bf16( b + dinv[i]*(hs[i] + sum_j hs[j]) ) ----
__global__ __launch_bounds__(256) void spmm_k(const unsigned* __restrict__ hs,
    const int* __restrict__ coff, const int* __restrict__ rows,
    const float* __restrict__ dinv, const float* __restrict__ bias,
    unsigned* __restrict__ outh) {
  int node = blockIdx.x * 4 + (threadIdx.x >> 6);
  int lane = threadIdx.x & 63;
  unsigned su = hs[(size_t)node * 64 + lane];        // self term
  float a0x = __uint_as_float(su << 16), a0y = __uint_as_float(su & 0xffff0000u);
  float a1x = 0.f, a1y = 0.f, a2x = 0.f, a2y = 0.f, a3x = 0.f, a3y = 0.f;
  int s = coff[node], e = coff[node + 1];
  int p = s;
  for (; p + 4 <= e; p += 4) {
    int j0 = rows[p], j1 = rows[p + 1], j2 = rows[p + 2], j3 = rows[p + 3];
    unsigned u0 = hs[(size_t)j0 * 64 + lane];
    unsigned u1 = hs[(size_t)j1 * 64 + lane];
    unsigned u2 = hs[(size_t)j2 * 64 + lane];
    unsigned u3 = hs[(size_t)j3 * 64 + lane];
    a0x += __uint_as_float(u0 << 16); a0y += __uint_as_float(u0 & 0xffff0000u);
    a1x += __uint_as_float(u1 << 16); a1y += __uint_as_float(u1 & 0xffff0000u);
    a2x += __uint_as_float(u2 << 16); a2y += __uint_as_float(u2 & 0xffff0000u);
    a3x += __uint_as_float(u3 << 16); a3y += __uint_as_float(u3 & 0xffff0000u);
  }
  for (; p < e; ++p) {
    int j = rows[p];
    unsigned u = hs[(size_t)j * 64 + lane];
    a1x += __uint_as_float(u << 16); a1y += __uint_as_float(u & 0xffff0000u);
  }
  float di = dinv[node];
  float2 b = reinterpret_cast<const float2*>(bias)[lane];
  float ox = b.x + di * ((a0x + a1x) + (a2x + a3x));
  float oy = b.y + di * ((a0y + a1y) + (a2y + a3y));
  outh[(size_t)node * 64 + lane] = rtne16(ox) | (rtne16(oy) << 16);
}

// ---- pooling over bf16 h: per (graph, chunk) block; relu fused; max via int atomics ----
__global__ __launch_bounds__(128) void pool_k(const unsigned short* __restrict__ h,
    const int* __restrict__ batch, float* __restrict__ gfeat) {
  int g = blockIdx.x >> 4;
  int c = blockIdx.x & 15;
  int f = threadIdx.x;
  int lo = lbound(batch, NNODES, g);
  int hi = lbound(batch, NNODES, g + 1);
  int len = hi - lo;
  int cs = lo + ((len * c) >> 4);
  int ce = lo + ((len * (c + 1)) >> 4);
  float mx = 0.f, sm = 0.f;
  for (int n = cs; n < ce; ++n) {
    float v = __uint_as_float((unsigned)h[(size_t)n * FHID + f] << 16);
    v = fmaxf(v, 0.f);
    mx = fmaxf(mx, v);
    sm += v;
  }
  atomicMax(reinterpret_cast<int*>(&gfeat[g * 256 + f]), __float_as_int(mx));
  atomicAdd(&gfeat[g * 256 + 128 + f], sm);
}

// ---- MLP head + log_softmax: one block per graph ----
__global__ __launch_bounds__(128) void mlp_k(const float* __restrict__ gfeat,
    const int* __restrict__ batch,
    const float* __restrict__ Wl1, const float* __restrict__ bl1,
    const float* __restrict__ Wl2, const float* __restrict__ bl2,
    const float* __restrict__ Wl3, const float* __restrict__ bl3,
    float* __restrict__ out) {
  int g = blockIdx.x;
  int t = threadIdx.x;
  __shared__ float gv[256];
  __shared__ float a1[128];
  __shared__ float a2[64];
  __shared__ float z[NCLASSES];
  __shared__ float red[2];
  int lo = lbound(batch, NNODES, g);
  int hi = lbound(batch, NNODES, g + 1);
  float invc = 1.0f / (float)max(hi - lo, 1);
  gv[t] = gfeat[g * 256 + t];                       // gmp (bits written by atomicMax)
  gv[128 + t] = gfeat[g * 256 + 128 + t] * invc;    // gap = sum/cnt
  __syncthreads();
  float s = bl1[t];
  for (int k = 0; k < 256; ++k) s += gv[k] * Wl1[k * 128 + t];
  a1[t] = fmaxf(s, 0.f);
  __syncthreads();
  if (t < 64) {
    float s2 = bl2[t];
    for (int k = 0; k < 128; ++k) s2 += a1[k] * Wl2[k * 64 + t];
    a2[t] = fmaxf(s2, 0.f);
  }
  __syncthreads();
  if (t < NCLASSES) {
    float s3 = bl3[t];
    for (int k = 0; k < 64; ++k) s3 += a2[k] * Wl3[k * NCLASSES + t];
    z[t] = s3;
  }
  __syncthreads();
  if (t == 0) {
    float m = z[0];
    for (int i = 1; i < NCLASSES; ++i) m = fmaxf(m, z[i]);
    float sum = 0.f;
    for (int i = 0; i < NCLASSES; ++i) sum += expf(z[i] - m);
    red[0] = m; red[1] = logf(sum);
  }
  __syncthreads();
  if (t < NCLASSES) out[g * NCLASSES + t] = z[t] - red[0] - red[1];
}

extern "C" void kernel_launch(void* const* d_in, const int* in_sizes, int n_in,
                              void* d_out, int out_size, void* d_ws, size_t ws_size,
                              hipStream_t stream) {
  const float* x     = (const float*)d_in[0];
  const int*   ei    = (const int*)d_in[1];
  const int*   batch = (const int*)d_in[2];
  const float* W1    = (const float*)d_in[3];
  const float* b1    = (const float*)d_in[4];
  const float* W2    = (const float*)d_in[5];
  const float* b2    = (const float*)d_in[6];
  const float* Wl1   = (const float*)d_in[7];
  const float* bl1   = (const float*)d_in[8];
  const float* Wl2   = (const float*)d_in[9];
  const float* bl2   = (const float*)d_in[10];
  const float* Wl3   = (const float*)d_in[11];
  const float* bl3   = (const float*)d_in[12];
  float* out = (float*)d_out;

  const int N = NNODES;
  const int E = in_sizes[1] / 2;
  const int* row = ei;       // sources
  const int* col = ei + E;   // targets
  const int NBLK = (E + CHUNK - 1) / CHUNK;  // 261

  char* ws = (char*)d_ws;
  size_t off = 0;
  auto alloc = [&](size_t bytes) {
    size_t cur = off;
    off += (bytes + 255) & ~(size_t)255;
    return (void*)(ws + cur);
  };
  float*    dinv  = (float*)alloc((size_t)N * 4);
  int*      coff  = (int*)alloc((size_t)(N + 1) * 4);
  int*      gcnt  = (int*)alloc((size_t)NBUCK * 4);
  int*      gcur  = (int*)alloc((size_t)NBUCK * 4);
  int*      bboff = (int*)alloc((size_t)(NBUCK + 1) * 4);
  int*      crows = (int*)alloc((size_t)E * 4);
  unsigned* bufHS = (unsigned*)alloc((size_t)N * 64 * 4);   // hs bf16-packed (25.6 MB)
  unsigned* bufH  = (unsigned*)alloc((size_t)N * 64 * 4);   // conv out bf16-packed (25.6 MB)
  float*    gfeat = (float*)alloc((size_t)NGRAPHS * 256 * 4);
  int2*     part  = (int2*)bufH;   // alias: part dead before bufH first written

  hipMemsetAsync(gcnt, 0, (size_t)NBUCK * 4, stream);
  hipMemsetAsync(gfeat, 0, (size_t)NGRAPHS * 256 * 4, stream);

  // CSR build (bucketed, locality-aware)
  hist_coarse_k<<<NBLK, 256, 0, stream>>>(col, E, gcnt);
  bucket_scan_k<<<1, 512, 0, stream>>>(gcnt, bboff, gcur, coff);
  partition_k<<<NBLK, 256, 0, stream>>>(row, col, E, gcur, part);
  fine_csr_k<<<NBUCK, 256, 0, stream>>>(part, bboff, crows, coff, dinv);

  const int GG = (N + 63) / 64;   // 1563
  // conv1
  gemm_mfma_k<0><<<GG, 256, 0, stream>>>(x, W1, dinv, bufHS, N);
  spmm_k<<<N / 4, 256, 0, stream>>>(bufHS, coff, crows, dinv, b1, bufH);
  // conv2 (relu fused into bf16 A-staging)
  gemm_mfma_k<1><<<GG, 256, 0, stream>>>(bufH, W2, dinv, bufHS, N);
  spmm_k<<<N / 4, 256, 0, stream>>>(bufHS, coff, crows, dinv, b2, bufH);

  // readout (relu fused into pool)
  pool_k<<<NGRAPHS * 16, 128, 0, stream>>>((const unsigned short*)bufH, batch, gfeat);
  mlp_k<<<NGRAPHS, 128, 0, stream>>>(gfeat, batch, Wl1, bl1, Wl2, bl2, Wl3, bl3, out);
}